// Round 20
// baseline (168.958 us; speedup 1.0000x reference)
//
#include <hip/hip_runtime.h>
#include <cstdint>
#include <cstddef>
#include <cmath>

// GPT-2 attention block: qkv = x@Wa + ba ; causal softmax(QK^T) V ; out = a@Wp + bp
// B=4 S=2048 D=1024 H=16 hd=64. All matmuls in bf16 MFMA (fp32 accum).
// Round-18 base (156.4 us) + attn delta, re-tried with compiler-known exp2f
// (round-14/19 failures attributed to raw inline-asm v_exp_f32 TRANS-use hazard).

using f32x4  = __attribute__((ext_vector_type(4))) float;
using f32x16 = __attribute__((ext_vector_type(16))) float;
using bf8    = __attribute__((ext_vector_type(8))) __bf16;

static __device__ __forceinline__ short f2bf(float f) {
  union { float f; unsigned u; } v; v.f = f;
  unsigned r = v.u + 0x7fffu + ((v.u >> 16) & 1u);  // RNE
  return (short)(r >> 16);
}

static __device__ __forceinline__ bf8 ldbf8(const short* p) { return *(const bf8*)p; }

static __device__ __forceinline__ f32x4 mfma16(bf8 a, bf8 b, f32x4 c) {
  return __builtin_amdgcn_mfma_f32_16x16x32_bf16(a, b, c, 0, 0, 0);
}
static __device__ __forceinline__ f32x16 mfma32(bf8 a, bf8 b, f32x16 c) {
  return __builtin_amdgcn_mfma_f32_32x32x16_bf16(a, b, c, 0, 0, 0);
}

static __device__ __forceinline__ void gload16(const void* g, void* l) {
  __builtin_amdgcn_global_load_lds((const __attribute__((address_space(1))) void*)g,
                                   (__attribute__((address_space(3))) void*)l, 16, 0, 0);
}

static __device__ __forceinline__ unsigned cvtpk(float a, float b) {
  unsigned r;
  asm("v_cvt_pk_bf16_f32 %0, %1, %2" : "=v"(r) : "v"(a), "v"(b));
  return r;
}
static __device__ __forceinline__ void permswap(unsigned& a, unsigned& b) {
  asm("v_permlane32_swap_b32 %0, %1" : "+v"(a), "+v"(b));
}

// vmcnt(N) + raw barrier + compiler memory fence
#define KWAIT(N) do { asm volatile("s_waitcnt vmcnt(" #N ")" ::: "memory"); \
    __builtin_amdgcn_s_barrier(); asm volatile("" ::: "memory"); } while (0)

#define LGKM_GATE() do { \
    asm volatile("s_waitcnt lgkmcnt(0)" ::: "memory"); \
    __builtin_amdgcn_sched_barrier(0); } while (0)

// ---------------- fused prep: cast x -> bf16 ; transpose+cast both weight mats ----------
__global__ __launch_bounds__(256) void k_prep(const float* __restrict__ x,
                                              const float* __restrict__ Wa,
                                              const float* __restrict__ Wp,
                                              short* __restrict__ Xb,
                                              short* __restrict__ Wta,
                                              short* __restrict__ Wtp) {
  int bid = blockIdx.x, t = threadIdx.x;
  if (bid < 8192) {
    int i = bid * 256 + t;
    float4 v = ((const float4*)x)[i];
    short4 o; o.x = f2bf(v.x); o.y = f2bf(v.y); o.z = f2bf(v.z); o.w = f2bf(v.w);
    ((short4*)Xb)[i] = o;
    return;
  }
  __shared__ short Ls[64][66];
  const float* W; short* Wt; int N, idx;
  if (bid < 8960) { W = Wa; Wt = Wta; N = 3072; idx = bid - 8192; }
  else            { W = Wp; Wt = Wtp; N = 1024; idx = bid - 8960; }
  int k0 = (idx & 15) * 64, n0 = (idx >> 4) * 64;
#pragma unroll
  for (int p = 0; p < 16; ++p) {
    int ii = p * 256 + t;
    int kk = ii >> 6, nn = ii & 63;
    Ls[kk][nn] = f2bf(W[(size_t)(k0 + kk) * N + n0 + nn]);
  }
  __syncthreads();
#pragma unroll
  for (int p = 0; p < 16; ++p) {
    int ii = p * 256 + t;
    int nn = ii >> 6, kk = ii & 63;
    Wt[(size_t)(n0 + nn) * 1024 + k0 + kk] = Ls[kk][nn];
  }
}

// ---------------- qkv GEMM (best): BM=128 BN=256 BK=64, 3 bufs, lookahead-2 ----
// Q columns pre-scaled by log2(e) so attention can use exp2f (native v_exp_f32).
__global__ __launch_bounds__(512, 2) void k_gemm11q(const short* __restrict__ Ag, const short* __restrict__ Bg,
                                                    const float* __restrict__ bias,
                                                    short* __restrict__ Qb, short* __restrict__ Kb,
                                                    short* __restrict__ VbT) {
  constexpr int NTN = 12;                        // N-tiles of 256
  constexpr int NWG = 64 * NTN;                  // 768 = 3 exact CU rounds
  __shared__ __align__(16) short As[3][128 * 64];   // 48 KB
  __shared__ __align__(16) short Bs[3][256 * 64];   // 96 KB
  int bid = blockIdx.x;
  int wg = (bid & 7) * (NWG >> 3) + (bid >> 3);  // bijective XCD swizzle (NWG%8==0)
  int m0 = (wg / NTN) * 128, n0 = (wg % NTN) * 256;
  int t = threadIdx.x, w = t >> 6, l = t & 63;
  int wm = w >> 2, wn = w & 3;                   // 2M x 4N -> per-wave 64x64
  int lg = l >> 4, l15 = l & 15;

  int srow = w * 8 + (l >> 3);
  int sswz = ((l & 7) ^ (srow & 7)) * 8;
  const short* aSrc = Ag + (size_t)(m0 + srow) * 1024 + sswz;
  const short* bSrc = Bg + (size_t)(n0 + srow) * 1024 + sswz;

  int aoff[4][2], boff[4][2];
#pragma unroll
  for (int mi = 0; mi < 4; ++mi)
#pragma unroll
    for (int ks = 0; ks < 2; ++ks) {
      int rr = wm * 64 + mi * 16 + l15;
      aoff[mi][ks] = rr * 64 + (((ks * 4 + lg) ^ (rr & 7)) * 8);
    }
#pragma unroll
  for (int nj = 0; nj < 4; ++nj)
#pragma unroll
    for (int ks = 0; ks < 2; ++ks) {
      int rr = wn * 64 + nj * 16 + l15;
      boff[nj][ks] = rr * 64 + (((ks * 4 + lg) ^ (rr & 7)) * 8);
    }
  f32x4 acc[4][4] = {};

#define STG_A(kt, bf) do { \
    _Pragma("unroll") for (int g = 0; g < 2; ++g) \
      gload16(aSrc + (size_t)g * 65536 + (kt) * 64, &As[bf][(g * 64 + w * 8) * 64]); } while (0)
#define STG_B01(kt, bf) do { \
    _Pragma("unroll") for (int g = 0; g < 2; ++g) \
      gload16(bSrc + (size_t)g * 65536 + (kt) * 64, &Bs[bf][(g * 64 + w * 8) * 64]); } while (0)
#define STG_B23(kt, bf) do { \
    _Pragma("unroll") for (int g = 2; g < 4; ++g) \
      gload16(bSrc + (size_t)g * 65536 + (kt) * 64, &Bs[bf][(g * 64 + w * 8) * 64]); } while (0)

  STG_A(0, 0); STG_B01(0, 0); STG_B23(0, 0);
  STG_A(1, 1); STG_B01(1, 1); STG_B23(1, 1);
  int cur = 0;
  for (int kt = 0; kt < 16; ++kt) {
    if (kt == 15) { KWAIT(0); } else { KWAIT(6); }
    int nxt = cur + 2; if (nxt >= 3) nxt -= 3;
    const short* Ab = As[cur];
    const short* Bb = Bs[cur];
    // ---- P1: A01 + all B frags ; stage T+2 A,B01 ; MFMA m01 ----
    bf8 a01[2][2], bfr[4][2];
#pragma unroll
    for (int mi = 0; mi < 2; ++mi)
#pragma unroll
      for (int ks = 0; ks < 2; ++ks) a01[mi][ks] = ldbf8(Ab + aoff[mi][ks]);
#pragma unroll
    for (int nj = 0; nj < 4; ++nj)
#pragma unroll
      for (int ks = 0; ks < 2; ++ks) bfr[nj][ks] = ldbf8(Bb + boff[nj][ks]);
    asm volatile("" ::: "memory");
    if (kt + 2 < 16) { STG_A(kt + 2, nxt); STG_B01(kt + 2, nxt); }
    LGKM_GATE();
    __builtin_amdgcn_s_setprio(1);
#pragma unroll
    for (int mi = 0; mi < 2; ++mi)
#pragma unroll
      for (int nj = 0; nj < 4; ++nj) {
        acc[mi][nj] = mfma16(a01[mi][0], bfr[nj][0], acc[mi][nj]);
        acc[mi][nj] = mfma16(a01[mi][1], bfr[nj][1], acc[mi][nj]);
      }
    __builtin_amdgcn_s_setprio(0);
    __builtin_amdgcn_s_barrier();
    // ---- P2: A23 frags ; stage T+2 B23 ; MFMA m23 ----
    bf8 a23[2][2];
#pragma unroll
    for (int mi = 0; mi < 2; ++mi)
#pragma unroll
      for (int ks = 0; ks < 2; ++ks) a23[mi][ks] = ldbf8(Ab + aoff[2 + mi][ks]);
    asm volatile("" ::: "memory");
    if (kt + 2 < 16) { STG_B23(kt + 2, nxt); }
    LGKM_GATE();
    __builtin_amdgcn_s_setprio(1);
#pragma unroll
    for (int mi = 0; mi < 2; ++mi)
#pragma unroll
      for (int nj = 0; nj < 4; ++nj) {
        acc[2 + mi][nj] = mfma16(a23[mi][0], bfr[nj][0], acc[2 + mi][nj]);
        acc[2 + mi][nj] = mfma16(a23[mi][1], bfr[nj][1], acc[2 + mi][nj]);
      }
    __builtin_amdgcn_s_setprio(0);
    cur = (cur == 2) ? 0 : cur + 1;
  }
#undef STG_A
#undef STG_B01
#undef STG_B23

  float bv[4];
#pragma unroll
  for (int nj = 0; nj < 4; ++nj) bv[nj] = bias[n0 + wn * 64 + nj * 16 + l15];
  int whichB = n0 >> 10;                      // block-constant: 0=Q 1=K 2=V
  float qs = (whichB == 0) ? 1.44269504f : 1.0f;
#pragma unroll
  for (int mi = 0; mi < 4; ++mi) {
    int gr0 = m0 + wm * 64 + mi * 16 + lg * 4;
    int bq = gr0 >> 11, s0 = gr0 & 2047;
#pragma unroll
    for (int nj = 0; nj < 4; ++nj) {
      int gc = n0 + wn * 64 + nj * 16 + l15;
      int rem = gc & 1023;
      int hh = rem >> 6, dd = rem & 63;
      if (whichB == 2) {
        short4 pk;
        pk.x = f2bf(acc[mi][nj][0] + bv[nj]);
        pk.y = f2bf(acc[mi][nj][1] + bv[nj]);
        pk.z = f2bf(acc[mi][nj][2] + bv[nj]);
        pk.w = f2bf(acc[mi][nj][3] + bv[nj]);
        *(short4*)&VbT[((size_t)((bq * 16 + hh) * 64 + dd)) * 2048 + s0] = pk;
      } else {
        short* dst = whichB == 0 ? Qb : Kb;
#pragma unroll
        for (int r = 0; r < 4; ++r)
          dst[((size_t)((bq * 16 + hh) * 2048 + (s0 + r))) * 64 + dd] = f2bf((acc[mi][nj][r] + bv[nj]) * qs);
      }
    }
  }
}

// ---------------- proj GEMM v14: 128x128, BK=64, 4 waves, 2 bufs, 2 blocks/CU ----------
__global__ __launch_bounds__(256, 2) void k_gemm14p(const short* __restrict__ Ag, const short* __restrict__ Bg,
                                                    const float* __restrict__ bias, float* __restrict__ Out) {
  constexpr int NTN = 8;
  constexpr int NWG = 64 * NTN;                  // 512 = 2 blocks/CU exact
  __shared__ __align__(16) short As[2][128 * 64];
  __shared__ __align__(16) short Bs[2][128 * 64];
  int bid = blockIdx.x;
  int wg = (bid & 7) * (NWG >> 3) + (bid >> 3);
  int m0 = (wg / NTN) * 128, n0 = (wg % NTN) * 128;
  int t = threadIdx.x, w = t >> 6, l = t & 63;
  int wm = w >> 1, wn = w & 1;
  int lg = l >> 4, l15 = l & 15;

  int sswz = ((t & 7) ^ ((t >> 3) & 7)) * 8;
  const short* aSrc = Ag + (size_t)(m0 + (t >> 3)) * 1024 + sswz;
  const short* bSrc = Bg + (size_t)(n0 + (t >> 3)) * 1024 + sswz;

  int aoff[4][2], boff[4][2];
#pragma unroll
  for (int mi = 0; mi < 4; ++mi)
#pragma unroll
    for (int ks = 0; ks < 2; ++ks) {
      int rr = wm * 64 + mi * 16 + l15;
      aoff[mi][ks] = rr * 64 + (((ks * 4 + lg) ^ (rr & 7)) * 8);
    }
#pragma unroll
  for (int nj = 0; nj < 4; ++nj)
#pragma unroll
    for (int ks = 0; ks < 2; ++ks) {
      int rr = wn * 64 + nj * 16 + l15;
      boff[nj][ks] = rr * 64 + (((ks * 4 + lg) ^ (rr & 7)) * 8);
    }
  f32x4 acc[4][4] = {};

  auto STAGE = [&](int kt, int bf) {
#pragma unroll
    for (int g = 0; g < 4; ++g)
      gload16(aSrc + (size_t)(g * 32) * 1024 + kt * 64, &As[bf][g * 2048 + w * 512]);
#pragma unroll
    for (int g = 0; g < 4; ++g)
      gload16(bSrc + (size_t)(g * 32) * 1024 + kt * 64, &Bs[bf][g * 2048 + w * 512]);
  };

  STAGE(0, 0);
  STAGE(1, 1);
  for (int kt = 0; kt < 16; ++kt) {
    if (kt == 15) { KWAIT(0); } else { KWAIT(8); }
    const short* Ab = As[kt & 1];
    const short* Bb = Bs[kt & 1];
    bf8 af[4][2], bfr[4][2];
#pragma unroll
    for (int mi = 0; mi < 4; ++mi)
#pragma unroll
      for (int ks = 0; ks < 2; ++ks) af[mi][ks] = ldbf8(Ab + aoff[mi][ks]);
#pragma unroll
    for (int nj = 0; nj < 4; ++nj)
#pragma unroll
      for (int ks = 0; ks < 2; ++ks) bfr[nj][ks] = ldbf8(Bb + boff[nj][ks]);
    __builtin_amdgcn_s_setprio(1);
#pragma unroll
    for (int mi = 0; mi < 4; ++mi)
#pragma unroll
      for (int nj = 0; nj < 4; ++nj) {
        acc[mi][nj] = mfma16(af[mi][0], bfr[nj][0], acc[mi][nj]);
        acc[mi][nj] = mfma16(af[mi][1], bfr[nj][1], acc[mi][nj]);
      }
    __builtin_amdgcn_s_setprio(0);
    __builtin_amdgcn_s_barrier();
    asm volatile("" ::: "memory");
    if (kt + 2 < 16) STAGE(kt + 2, kt & 1);
  }

  float bv[4];
#pragma unroll
  for (int nj = 0; nj < 4; ++nj) bv[nj] = bias[n0 + wn * 64 + nj * 16 + l15];
#pragma unroll
  for (int mi = 0; mi < 4; ++mi) {
    int gr0 = m0 + wm * 64 + mi * 16 + lg * 4;
#pragma unroll
    for (int nj = 0; nj < 4; ++nj) {
      int gc = n0 + wn * 64 + nj * 16 + l15;
#pragma unroll
      for (int r = 0; r < 4; ++r)
        Out[(size_t)(gr0 + r) * 1024 + gc] = acc[mi][nj][r] + bv[nj];
    }
  }
}

// ---------------- Flash attention v7b: v6 + exp2f (Q pre-scaled) + masked-kb skip ----------
static __device__ __forceinline__ void stage_kv4(const short* __restrict__ Kg, const short* __restrict__ Vg,
                                                 short* KsB, short* VsB, int w, int l, int kv0) {
#pragma unroll
  for (int i = 0; i < 4; ++i) {
    int k = i * 32 + w * 8 + (l >> 3);
    int c = (l & 7) ^ (k & 7);
    gload16(Kg + (size_t)(kv0 + k) * 64 + c * 8, KsB + i * 2048 + w * 512);
  }
#pragma unroll
  for (int i = 0; i < 4; ++i) {
    int d = i * 16 + w * 4 + (l >> 4);
    int s = l & 15;
    int c = (s & 8) | ((s & 7) ^ (d & 7));
    gload16(Vg + (size_t)d * 2048 + kv0 + c * 8, VsB + i * 2048 + w * 512);
  }
}

template <bool MASK>
static __device__ __forceinline__ void attn_tile(const short* __restrict__ KsB, const short* __restrict__ VsB,
                                                 const bf8* qf, f32x16* oa, float& lsum,
                                                 int kv0, int qg, int qw, int hi, int l31, int l7) {
  bf8 pfr[8];
#pragma unroll
  for (int kb = 0; kb < 4; ++kb) {
    if (MASK && kv0 + 32 * kb > qw + 31) {       // wave-uniform: whole 32-kv block masked
      union { unsigned u[4]; bf8 v; } zz = {{0u, 0u, 0u, 0u}};
      pfr[2 * kb] = zz.v; pfr[2 * kb + 1] = zz.v;
      continue;
    }
    f32x16 sv = {};
#pragma unroll
    for (int dk = 0; dk < 4; ++dk) {
      bf8 kf = ldbf8(&KsB[(32 * kb + l31) * 64 + (((2 * dk + hi) ^ l7) * 8)]);
      sv = mfma32(kf, qf[dk], sv);
    }
    float pe[16];
#pragma unroll
    for (int r = 0; r < 16; ++r) {
      float e = exp2f(sv[r]);                    // Q pre-scaled by log2e; compiler-known op
      if constexpr (MASK) {
        int kg = kv0 + 32 * kb + ((r & 3) + 8 * (r >> 2) + 4 * hi);
        e = (kg > qg) ? 0.f : e;
      }
      pe[r] = e;
      lsum += e;
    }
#pragma unroll
    for (int rh = 0; rh < 2; ++rh) {
      unsigned a01 = cvtpk(pe[8 * rh + 0], pe[8 * rh + 1]);
      unsigned a23 = cvtpk(pe[8 * rh + 2], pe[8 * rh + 3]);
      unsigned b01 = cvtpk(pe[8 * rh + 4], pe[8 * rh + 5]);
      unsigned b23 = cvtpk(pe[8 * rh + 6], pe[8 * rh + 7]);
      permswap(a01, b01);
      permswap(a23, b23);
      union { unsigned u[4]; bf8 v; } fu;
      fu.u[0] = a01; fu.u[1] = a23; fu.u[2] = b01; fu.u[3] = b23;
      pfr[2 * kb + rh] = fu.v;
    }
  }
#pragma unroll
  for (int db = 0; db < 2; ++db) {
#pragma unroll
    for (int ks = 0; ks < 8; ++ks) {
      if (MASK && kv0 + 32 * (ks >> 1) > qw + 31) continue;   // P==0 for this k-slot
      int c = 2 * ks + hi;
      bf8 vf = ldbf8(&VsB[(32 * db + l31) * 128 + (((c & 8) | ((c & 7) ^ l7)) * 8)]);
      oa[db] = mfma32(pfr[ks], vf, oa[db]);
    }
  }
}

static __device__ __forceinline__ void attn_writeout(short* __restrict__ A2, const f32x16* oa, float lsum,
                                                     int b, int h, int qw, int hi, int l31) {
  float lf = lsum + __shfl_xor(lsum, 32, 64);
#pragma unroll
  for (int r = 0; r < 16; ++r) {
    int cr = (r & 3) + 8 * (r >> 2) + 4 * hi;
    float li = __shfl(lf, cr, 64);
    float ri = 1.0f / li;
    size_t row = (size_t)(b * 2048 + qw + cr) * 1024 + h * 64 + l31;
#pragma unroll
    for (int db = 0; db < 2; ++db)
      A2[row + 32 * db] = f2bf(oa[db][r] * ri);
  }
}

__global__ __launch_bounds__(256, 2) void k_attn(const short* __restrict__ Q, const short* __restrict__ K,
                                                 const short* __restrict__ VT, short* __restrict__ A2) {
  __shared__ __align__(16) short Ks[2][128 * 64];
  __shared__ __align__(16) short Vs[2][64 * 128];
  int bh = blockIdx.x;
  int bx = blockIdx.y;                // 0..7, q-tile pair (bx, 15-bx): 17 KV tiles
  int b = bh >> 4, h = bh & 15;
  int t = threadIdx.x, w = t >> 6, l = t & 63;
  int hi = l >> 5, l31 = l & 31, l7 = l & 7;
  const short* Qg = Q + (size_t)bh * 2048 * 64;
  const short* Kg = K + (size_t)bh * 2048 * 64;
  const short* Vg = VT + (size_t)bh * 64 * 2048;

  int qt0 = bx, qt1 = 15 - bx;
  int nt0 = qt0 + 1;
  int total = nt0 + qt1 + 1;          // 17

  const f32x16 ZERO = {};
  f32x16 oa[2] = {};
  float lsum = 0.f;

  int qw = qt0 * 128 + w * 32;
  int qg = qw + l31;
  bf8 qf[4];
#pragma unroll
  for (int dk = 0; dk < 4; ++dk) qf[dk] = ldbf8(Qg + (size_t)qg * 64 + dk * 16 + hi * 8);

  stage_kv4(Kg, Vg, Ks[0], Vs[0], w, l, 0);
  {
    int t1 = (1 >= nt0) ? (1 - nt0) : 1;
    stage_kv4(Kg, Vg, Ks[1], Vs[1], w, l, t1 * 128);
  }

  for (int i = 0; i < total; ++i) {
    if (i == total - 1) { KWAIT(0); } else { KWAIT(8); }
    int buf = i & 1;
    int kv0 = ((i >= nt0) ? (i - nt0) : i) * 128;
    if (kv0 <= qw + 31) {
      if (kv0 + 127 > qw) attn_tile<true >(Ks[buf], Vs[buf], qf, oa, lsum, kv0, qg, qw, hi, l31, l7);
      else                attn_tile<false>(Ks[buf], Vs[buf], qf, oa, lsum, kv0, qg, qw, hi, l31, l7);
    }
    if (i == nt0 - 1) {
      attn_writeout(A2, oa, lsum, b, h, qw, hi, l31);
      oa[0] = ZERO; oa[1] = ZERO; lsum = 0.f;
      qw = qt1 * 128 + w * 32;
      qg = qw + l31;
#pragma unroll
      for (int dk = 0; dk < 4; ++dk) qf[dk] = ldbf8(Qg + (size_t)qg * 64 + dk * 16 + hi * 8);
    }
    __builtin_amdgcn_s_barrier();
    asm volatile("" ::: "memory");
    if (i + 2 < total) {
      int tn = (i + 2 >= nt0) ? (i + 2 - nt0) : (i + 2);
      stage_kv4(Kg, Vg, Ks[buf], Vs[buf], w, l, tn * 128);
    }
  }
  attn_writeout(A2, oa, lsum, b, h, qw, hi, l31);
}

extern "C" void kernel_launch(void* const* d_in, const int* in_sizes, int n_in,
                              void* d_out, int out_size, void* d_ws, size_t ws_size,
                              hipStream_t stream) {
  const float* x      = (const float*)d_in[0];
  const float* w_attn = (const float*)d_in[1];
  const float* b_attn = (const float*)d_in[2];
  const float* w_proj = (const float*)d_in[3];
  const float* b_proj = (const float*)d_in[4];
  float* out = (float*)d_out;
  char* ws = (char*)d_ws;
  if (ws_size < 92274688u) return;  // need 88 MB scratch
  short* Xb  = (short*)(ws);                 // [8192][1024] bf16
  short* Wta = (short*)(ws + 16777216);      // [3072][1024] bf16 (W^T)
  short* Wtp = (short*)(ws + 23068672);      // [1024][1024] bf16 (W^T)
  short* Qb  = (short*)(ws + 25165824);      // [64 bh][2048][64]  (scaled by log2e)
  short* Kb  = (short*)(ws + 41943040);      // [64 bh][2048][64]
  short* VbT = (short*)(ws + 58720256);      // [64 bh][64 d][2048 s]
  short* A2  = (short*)(ws + 75497472);      // [8192][1024] bf16

  hipLaunchKernelGGL(k_prep, dim3(9216), dim3(256), 0, stream, x, w_attn, w_proj, Xb, Wta, Wtp);
  hipLaunchKernelGGL(k_gemm11q, dim3(768), dim3(512), 0, stream, Xb, Wta, b_attn, Qb, Kb, VbT);
  hipLaunchKernelGGL(k_attn, dim3(64, 8), dim3(256), 0, stream, Qb, Kb, VbT, A2);
  hipLaunchKernelGGL(k_gemm14p, dim3(512), dim3(256), 0, stream, A2, Wtp, b_proj, out);
}

// Round 21
// 152.662 us; speedup vs baseline: 1.1067x; 1.1067x over previous
//
#include <hip/hip_runtime.h>
#include <cstdint>
#include <cstddef>

// GPT-2 attention block: qkv = x@Wa + ba ; causal softmax(QK^T) V ; out = a@Wp + bp
// B=4 S=2048 D=1024 H=16 hd=64. All matmuls in bf16 MFMA (fp32 accum).
// Round-18 base (156.4 us) + ONE delta: attn exp via __builtin_amdgcn_exp2f
// (Q pre-scaled by log2e in qkv epilogue). No masked-kb skip (proven -23 us in r20).

using f32x4  = __attribute__((ext_vector_type(4))) float;
using f32x16 = __attribute__((ext_vector_type(16))) float;
using bf8    = __attribute__((ext_vector_type(8))) __bf16;

static __device__ __forceinline__ short f2bf(float f) {
  union { float f; unsigned u; } v; v.f = f;
  unsigned r = v.u + 0x7fffu + ((v.u >> 16) & 1u);  // RNE
  return (short)(r >> 16);
}

static __device__ __forceinline__ bf8 ldbf8(const short* p) { return *(const bf8*)p; }

static __device__ __forceinline__ f32x4 mfma16(bf8 a, bf8 b, f32x4 c) {
  return __builtin_amdgcn_mfma_f32_16x16x32_bf16(a, b, c, 0, 0, 0);
}
static __device__ __forceinline__ f32x16 mfma32(bf8 a, bf8 b, f32x16 c) {
  return __builtin_amdgcn_mfma_f32_32x32x16_bf16(a, b, c, 0, 0, 0);
}

static __device__ __forceinline__ void gload16(const void* g, void* l) {
  __builtin_amdgcn_global_load_lds((const __attribute__((address_space(1))) void*)g,
                                   (__attribute__((address_space(3))) void*)l, 16, 0, 0);
}

static __device__ __forceinline__ unsigned cvtpk(float a, float b) {
  unsigned r;
  asm("v_cvt_pk_bf16_f32 %0, %1, %2" : "=v"(r) : "v"(a), "v"(b));
  return r;
}
static __device__ __forceinline__ void permswap(unsigned& a, unsigned& b) {
  asm("v_permlane32_swap_b32 %0, %1" : "+v"(a), "+v"(b));
}

// vmcnt(N) + raw barrier + compiler memory fence
#define KWAIT(N) do { asm volatile("s_waitcnt vmcnt(" #N ")" ::: "memory"); \
    __builtin_amdgcn_s_barrier(); asm volatile("" ::: "memory"); } while (0)

#define LGKM_GATE() do { \
    asm volatile("s_waitcnt lgkmcnt(0)" ::: "memory"); \
    __builtin_amdgcn_sched_barrier(0); } while (0)

// ---------------- fused prep: cast x -> bf16 ; transpose+cast both weight mats ----------
__global__ __launch_bounds__(256) void k_prep(const float* __restrict__ x,
                                              const float* __restrict__ Wa,
                                              const float* __restrict__ Wp,
                                              short* __restrict__ Xb,
                                              short* __restrict__ Wta,
                                              short* __restrict__ Wtp) {
  int bid = blockIdx.x, t = threadIdx.x;
  if (bid < 8192) {
    int i = bid * 256 + t;
    float4 v = ((const float4*)x)[i];
    short4 o; o.x = f2bf(v.x); o.y = f2bf(v.y); o.z = f2bf(v.z); o.w = f2bf(v.w);
    ((short4*)Xb)[i] = o;
    return;
  }
  __shared__ short Ls[64][66];
  const float* W; short* Wt; int N, idx;
  if (bid < 8960) { W = Wa; Wt = Wta; N = 3072; idx = bid - 8192; }
  else            { W = Wp; Wt = Wtp; N = 1024; idx = bid - 8960; }
  int k0 = (idx & 15) * 64, n0 = (idx >> 4) * 64;
#pragma unroll
  for (int p = 0; p < 16; ++p) {
    int ii = p * 256 + t;
    int kk = ii >> 6, nn = ii & 63;
    Ls[kk][nn] = f2bf(W[(size_t)(k0 + kk) * N + n0 + nn]);
  }
  __syncthreads();
#pragma unroll
  for (int p = 0; p < 16; ++p) {
    int ii = p * 256 + t;
    int nn = ii >> 6, kk = ii & 63;
    Wt[(size_t)(n0 + nn) * 1024 + k0 + kk] = Ls[kk][nn];
  }
}

// ---------------- qkv GEMM (best): BM=128 BN=256 BK=64, 3 bufs, lookahead-2 ----
// Q columns pre-scaled by log2(e) so attention uses native v_exp_f32 (2^x).
__global__ __launch_bounds__(512, 2) void k_gemm11q(const short* __restrict__ Ag, const short* __restrict__ Bg,
                                                    const float* __restrict__ bias,
                                                    short* __restrict__ Qb, short* __restrict__ Kb,
                                                    short* __restrict__ VbT) {
  constexpr int NTN = 12;                        // N-tiles of 256
  constexpr int NWG = 64 * NTN;                  // 768 = 3 exact CU rounds
  __shared__ __align__(16) short As[3][128 * 64];   // 48 KB
  __shared__ __align__(16) short Bs[3][256 * 64];   // 96 KB
  int bid = blockIdx.x;
  int wg = (bid & 7) * (NWG >> 3) + (bid >> 3);  // bijective XCD swizzle (NWG%8==0)
  int m0 = (wg / NTN) * 128, n0 = (wg % NTN) * 256;
  int t = threadIdx.x, w = t >> 6, l = t & 63;
  int wm = w >> 2, wn = w & 3;                   // 2M x 4N -> per-wave 64x64
  int lg = l >> 4, l15 = l & 15;

  int srow = w * 8 + (l >> 3);
  int sswz = ((l & 7) ^ (srow & 7)) * 8;
  const short* aSrc = Ag + (size_t)(m0 + srow) * 1024 + sswz;
  const short* bSrc = Bg + (size_t)(n0 + srow) * 1024 + sswz;

  int aoff[4][2], boff[4][2];
#pragma unroll
  for (int mi = 0; mi < 4; ++mi)
#pragma unroll
    for (int ks = 0; ks < 2; ++ks) {
      int rr = wm * 64 + mi * 16 + l15;
      aoff[mi][ks] = rr * 64 + (((ks * 4 + lg) ^ (rr & 7)) * 8);
    }
#pragma unroll
  for (int nj = 0; nj < 4; ++nj)
#pragma unroll
    for (int ks = 0; ks < 2; ++ks) {
      int rr = wn * 64 + nj * 16 + l15;
      boff[nj][ks] = rr * 64 + (((ks * 4 + lg) ^ (rr & 7)) * 8);
    }
  f32x4 acc[4][4] = {};

#define STG_A(kt, bf) do { \
    _Pragma("unroll") for (int g = 0; g < 2; ++g) \
      gload16(aSrc + (size_t)g * 65536 + (kt) * 64, &As[bf][(g * 64 + w * 8) * 64]); } while (0)
#define STG_B01(kt, bf) do { \
    _Pragma("unroll") for (int g = 0; g < 2; ++g) \
      gload16(bSrc + (size_t)g * 65536 + (kt) * 64, &Bs[bf][(g * 64 + w * 8) * 64]); } while (0)
#define STG_B23(kt, bf) do { \
    _Pragma("unroll") for (int g = 2; g < 4; ++g) \
      gload16(bSrc + (size_t)g * 65536 + (kt) * 64, &Bs[bf][(g * 64 + w * 8) * 64]); } while (0)

  STG_A(0, 0); STG_B01(0, 0); STG_B23(0, 0);
  STG_A(1, 1); STG_B01(1, 1); STG_B23(1, 1);
  int cur = 0;
  for (int kt = 0; kt < 16; ++kt) {
    if (kt == 15) { KWAIT(0); } else { KWAIT(6); }
    int nxt = cur + 2; if (nxt >= 3) nxt -= 3;
    const short* Ab = As[cur];
    const short* Bb = Bs[cur];
    // ---- P1: A01 + all B frags ; stage T+2 A,B01 ; MFMA m01 ----
    bf8 a01[2][2], bfr[4][2];
#pragma unroll
    for (int mi = 0; mi < 2; ++mi)
#pragma unroll
      for (int ks = 0; ks < 2; ++ks) a01[mi][ks] = ldbf8(Ab + aoff[mi][ks]);
#pragma unroll
    for (int nj = 0; nj < 4; ++nj)
#pragma unroll
      for (int ks = 0; ks < 2; ++ks) bfr[nj][ks] = ldbf8(Bb + boff[nj][ks]);
    asm volatile("" ::: "memory");
    if (kt + 2 < 16) { STG_A(kt + 2, nxt); STG_B01(kt + 2, nxt); }
    LGKM_GATE();
    __builtin_amdgcn_s_setprio(1);
#pragma unroll
    for (int mi = 0; mi < 2; ++mi)
#pragma unroll
      for (int nj = 0; nj < 4; ++nj) {
        acc[mi][nj] = mfma16(a01[mi][0], bfr[nj][0], acc[mi][nj]);
        acc[mi][nj] = mfma16(a01[mi][1], bfr[nj][1], acc[mi][nj]);
      }
    __builtin_amdgcn_s_setprio(0);
    __builtin_amdgcn_s_barrier();
    // ---- P2: A23 frags ; stage T+2 B23 ; MFMA m23 ----
    bf8 a23[2][2];
#pragma unroll
    for (int mi = 0; mi < 2; ++mi)
#pragma unroll
      for (int ks = 0; ks < 2; ++ks) a23[mi][ks] = ldbf8(Ab + aoff[2 + mi][ks]);
    asm volatile("" ::: "memory");
    if (kt + 2 < 16) { STG_B23(kt + 2, nxt); }
    LGKM_GATE();
    __builtin_amdgcn_s_setprio(1);
#pragma unroll
    for (int mi = 0; mi < 2; ++mi)
#pragma unroll
      for (int nj = 0; nj < 4; ++nj) {
        acc[2 + mi][nj] = mfma16(a23[mi][0], bfr[nj][0], acc[2 + mi][nj]);
        acc[2 + mi][nj] = mfma16(a23[mi][1], bfr[nj][1], acc[2 + mi][nj]);
      }
    __builtin_amdgcn_s_setprio(0);
    cur = (cur == 2) ? 0 : cur + 1;
  }
#undef STG_A
#undef STG_B01
#undef STG_B23

  float bv[4];
#pragma unroll
  for (int nj = 0; nj < 4; ++nj) bv[nj] = bias[n0 + wn * 64 + nj * 16 + l15];
  int whichB = n0 >> 10;                      // block-constant: 0=Q 1=K 2=V
  float qs = (whichB == 0) ? 1.44269504f : 1.0f;
#pragma unroll
  for (int mi = 0; mi < 4; ++mi) {
    int gr0 = m0 + wm * 64 + mi * 16 + lg * 4;
    int bq = gr0 >> 11, s0 = gr0 & 2047;
#pragma unroll
    for (int nj = 0; nj < 4; ++nj) {
      int gc = n0 + wn * 64 + nj * 16 + l15;
      int rem = gc & 1023;
      int hh = rem >> 6, dd = rem & 63;
      if (whichB == 2) {
        short4 pk;
        pk.x = f2bf(acc[mi][nj][0] + bv[nj]);
        pk.y = f2bf(acc[mi][nj][1] + bv[nj]);
        pk.z = f2bf(acc[mi][nj][2] + bv[nj]);
        pk.w = f2bf(acc[mi][nj][3] + bv[nj]);
        *(short4*)&VbT[((size_t)((bq * 16 + hh) * 64 + dd)) * 2048 + s0] = pk;
      } else {
        short* dst = whichB == 0 ? Qb : Kb;
#pragma unroll
        for (int r = 0; r < 4; ++r)
          dst[((size_t)((bq * 16 + hh) * 2048 + (s0 + r))) * 64 + dd] = f2bf((acc[mi][nj][r] + bv[nj]) * qs);
      }
    }
  }
}

// ---------------- proj GEMM v14: 128x128, BK=64, 4 waves, 2 bufs, 2 blocks/CU ----------
__global__ __launch_bounds__(256, 2) void k_gemm14p(const short* __restrict__ Ag, const short* __restrict__ Bg,
                                                    const float* __restrict__ bias, float* __restrict__ Out) {
  constexpr int NTN = 8;
  constexpr int NWG = 64 * NTN;                  // 512 = 2 blocks/CU exact
  __shared__ __align__(16) short As[2][128 * 64];
  __shared__ __align__(16) short Bs[2][128 * 64];
  int bid = blockIdx.x;
  int wg = (bid & 7) * (NWG >> 3) + (bid >> 3);
  int m0 = (wg / NTN) * 128, n0 = (wg % NTN) * 128;
  int t = threadIdx.x, w = t >> 6, l = t & 63;
  int wm = w >> 1, wn = w & 1;
  int lg = l >> 4, l15 = l & 15;

  int sswz = ((t & 7) ^ ((t >> 3) & 7)) * 8;
  const short* aSrc = Ag + (size_t)(m0 + (t >> 3)) * 1024 + sswz;
  const short* bSrc = Bg + (size_t)(n0 + (t >> 3)) * 1024 + sswz;

  int aoff[4][2], boff[4][2];
#pragma unroll
  for (int mi = 0; mi < 4; ++mi)
#pragma unroll
    for (int ks = 0; ks < 2; ++ks) {
      int rr = wm * 64 + mi * 16 + l15;
      aoff[mi][ks] = rr * 64 + (((ks * 4 + lg) ^ (rr & 7)) * 8);
    }
#pragma unroll
  for (int nj = 0; nj < 4; ++nj)
#pragma unroll
    for (int ks = 0; ks < 2; ++ks) {
      int rr = wn * 64 + nj * 16 + l15;
      boff[nj][ks] = rr * 64 + (((ks * 4 + lg) ^ (rr & 7)) * 8);
    }
  f32x4 acc[4][4] = {};

  auto STAGE = [&](int kt, int bf) {
#pragma unroll
    for (int g = 0; g < 4; ++g)
      gload16(aSrc + (size_t)(g * 32) * 1024 + kt * 64, &As[bf][g * 2048 + w * 512]);
#pragma unroll
    for (int g = 0; g < 4; ++g)
      gload16(bSrc + (size_t)(g * 32) * 1024 + kt * 64, &Bs[bf][g * 2048 + w * 512]);
  };

  STAGE(0, 0);
  STAGE(1, 1);
  for (int kt = 0; kt < 16; ++kt) {
    if (kt == 15) { KWAIT(0); } else { KWAIT(8); }
    const short* Ab = As[kt & 1];
    const short* Bb = Bs[kt & 1];
    bf8 af[4][2], bfr[4][2];
#pragma unroll
    for (int mi = 0; mi < 4; ++mi)
#pragma unroll
      for (int ks = 0; ks < 2; ++ks) af[mi][ks] = ldbf8(Ab + aoff[mi][ks]);
#pragma unroll
    for (int nj = 0; nj < 4; ++nj)
#pragma unroll
      for (int ks = 0; ks < 2; ++ks) bfr[nj][ks] = ldbf8(Bb + boff[nj][ks]);
    __builtin_amdgcn_s_setprio(1);
#pragma unroll
    for (int mi = 0; mi < 4; ++mi)
#pragma unroll
      for (int nj = 0; nj < 4; ++nj) {
        acc[mi][nj] = mfma16(af[mi][0], bfr[nj][0], acc[mi][nj]);
        acc[mi][nj] = mfma16(af[mi][1], bfr[nj][1], acc[mi][nj]);
      }
    __builtin_amdgcn_s_setprio(0);
    __builtin_amdgcn_s_barrier();
    asm volatile("" ::: "memory");
    if (kt + 2 < 16) STAGE(kt + 2, kt & 1);
  }

  float bv[4];
#pragma unroll
  for (int nj = 0; nj < 4; ++nj) bv[nj] = bias[n0 + wn * 64 + nj * 16 + l15];
#pragma unroll
  for (int mi = 0; mi < 4; ++mi) {
    int gr0 = m0 + wm * 64 + mi * 16 + lg * 4;
#pragma unroll
    for (int nj = 0; nj < 4; ++nj) {
      int gc = n0 + wn * 64 + nj * 16 + l15;
#pragma unroll
      for (int r = 0; r < 4; ++r)
        Out[(size_t)(gr0 + r) * 1024 + gc] = acc[mi][nj][r] + bv[nj];
    }
  }
}

// ---------------- Flash attention v6b: round-18 structure, native exp2 (no branches) ----
static __device__ __forceinline__ void stage_kv4(const short* __restrict__ Kg, const short* __restrict__ Vg,
                                                 short* KsB, short* VsB, int w, int l, int kv0) {
#pragma unroll
  for (int i = 0; i < 4; ++i) {
    int k = i * 32 + w * 8 + (l >> 3);
    int c = (l & 7) ^ (k & 7);
    gload16(Kg + (size_t)(kv0 + k) * 64 + c * 8, KsB + i * 2048 + w * 512);
  }
#pragma unroll
  for (int i = 0; i < 4; ++i) {
    int d = i * 16 + w * 4 + (l >> 4);
    int s = l & 15;
    int c = (s & 8) | ((s & 7) ^ (d & 7));
    gload16(Vg + (size_t)d * 2048 + kv0 + c * 8, VsB + i * 2048 + w * 512);
  }
}

template <bool MASK>
static __device__ __forceinline__ void attn_tile(const short* __restrict__ KsB, const short* __restrict__ VsB,
                                                 const bf8* qf, f32x16* oa, float& lsum,
                                                 int kv0, int qg, int hi, int l31, int l7) {
  bf8 pfr[8];
#pragma unroll
  for (int kb = 0; kb < 4; ++kb) {
    f32x16 sv = {};
#pragma unroll
    for (int dk = 0; dk < 4; ++dk) {
      bf8 kf = ldbf8(&KsB[(32 * kb + l31) * 64 + (((2 * dk + hi) ^ l7) * 8)]);
      sv = mfma32(kf, qf[dk], sv);
    }
    float pe[16];
#pragma unroll
    for (int r = 0; r < 16; ++r) {
      float e = __builtin_amdgcn_exp2f(sv[r]);   // Q pre-scaled by log2e; native 2^x
      if constexpr (MASK) {
        int kg = kv0 + 32 * kb + ((r & 3) + 8 * (r >> 2) + 4 * hi);
        e = (kg > qg) ? 0.f : e;
      }
      pe[r] = e;
      lsum += e;
    }
#pragma unroll
    for (int rh = 0; rh < 2; ++rh) {
      unsigned a01 = cvtpk(pe[8 * rh + 0], pe[8 * rh + 1]);
      unsigned a23 = cvtpk(pe[8 * rh + 2], pe[8 * rh + 3]);
      unsigned b01 = cvtpk(pe[8 * rh + 4], pe[8 * rh + 5]);
      unsigned b23 = cvtpk(pe[8 * rh + 6], pe[8 * rh + 7]);
      permswap(a01, b01);
      permswap(a23, b23);
      union { unsigned u[4]; bf8 v; } fu;
      fu.u[0] = a01; fu.u[1] = a23; fu.u[2] = b01; fu.u[3] = b23;
      pfr[2 * kb + rh] = fu.v;
    }
  }
#pragma unroll
  for (int db = 0; db < 2; ++db) {
#pragma unroll
    for (int ks = 0; ks < 8; ++ks) {
      int c = 2 * ks + hi;
      bf8 vf = ldbf8(&VsB[(32 * db + l31) * 128 + (((c & 8) | ((c & 7) ^ l7)) * 8)]);
      oa[db] = mfma32(pfr[ks], vf, oa[db]);
    }
  }
}

static __device__ __forceinline__ void attn_writeout(short* __restrict__ A2, const f32x16* oa, float lsum,
                                                     int b, int h, int qw, int hi, int l31) {
  float lf = lsum + __shfl_xor(lsum, 32, 64);
#pragma unroll
  for (int r = 0; r < 16; ++r) {
    int cr = (r & 3) + 8 * (r >> 2) + 4 * hi;
    float li = __shfl(lf, cr, 64);
    float ri = 1.0f / li;
    size_t row = (size_t)(b * 2048 + qw + cr) * 1024 + h * 64 + l31;
#pragma unroll
    for (int db = 0; db < 2; ++db)
      A2[row + 32 * db] = f2bf(oa[db][r] * ri);
  }
}

__global__ __launch_bounds__(256, 2) void k_attn(const short* __restrict__ Q, const short* __restrict__ K,
                                                 const short* __restrict__ VT, short* __restrict__ A2) {
  __shared__ __align__(16) short Ks[2][128 * 64];
  __shared__ __align__(16) short Vs[2][64 * 128];
  int bh = blockIdx.x;
  int bx = blockIdx.y;                // 0..7, q-tile pair (bx, 15-bx): 17 KV tiles
  int b = bh >> 4, h = bh & 15;
  int t = threadIdx.x, w = t >> 6, l = t & 63;
  int hi = l >> 5, l31 = l & 31, l7 = l & 7;
  const short* Qg = Q + (size_t)bh * 2048 * 64;
  const short* Kg = K + (size_t)bh * 2048 * 64;
  const short* Vg = VT + (size_t)bh * 64 * 2048;

  int qt0 = bx, qt1 = 15 - bx;
  int nt0 = qt0 + 1;
  int total = nt0 + qt1 + 1;          // 17

  const f32x16 ZERO = {};
  f32x16 oa[2] = {};
  float lsum = 0.f;

  int qw = qt0 * 128 + w * 32;
  int qg = qw + l31;
  bf8 qf[4];
#pragma unroll
  for (int dk = 0; dk < 4; ++dk) qf[dk] = ldbf8(Qg + (size_t)qg * 64 + dk * 16 + hi * 8);

  stage_kv4(Kg, Vg, Ks[0], Vs[0], w, l, 0);
  {
    int t1 = (1 >= nt0) ? (1 - nt0) : 1;
    stage_kv4(Kg, Vg, Ks[1], Vs[1], w, l, t1 * 128);
  }

  for (int i = 0; i < total; ++i) {
    if (i == total - 1) { KWAIT(0); } else { KWAIT(8); }
    int buf = i & 1;
    int kv0 = ((i >= nt0) ? (i - nt0) : i) * 128;
    if (kv0 <= qw + 31) {
      if (kv0 + 127 > qw) attn_tile<true >(Ks[buf], Vs[buf], qf, oa, lsum, kv0, qg, hi, l31, l7);
      else                attn_tile<false>(Ks[buf], Vs[buf], qf, oa, lsum, kv0, qg, hi, l31, l7);
    }
    if (i == nt0 - 1) {
      attn_writeout(A2, oa, lsum, b, h, qw, hi, l31);
      oa[0] = ZERO; oa[1] = ZERO; lsum = 0.f;
      qw = qt1 * 128 + w * 32;
      qg = qw + l31;
#pragma unroll
      for (int dk = 0; dk < 4; ++dk) qf[dk] = ldbf8(Qg + (size_t)qg * 64 + dk * 16 + hi * 8);
    }
    __builtin_amdgcn_s_barrier();
    asm volatile("" ::: "memory");
    if (i + 2 < total) {
      int tn = (i + 2 >= nt0) ? (i + 2 - nt0) : (i + 2);
      stage_kv4(Kg, Vg, Ks[buf], Vs[buf], w, l, tn * 128);
    }
  }
  attn_writeout(A2, oa, lsum, b, h, qw, hi, l31);
}

extern "C" void kernel_launch(void* const* d_in, const int* in_sizes, int n_in,
                              void* d_out, int out_size, void* d_ws, size_t ws_size,
                              hipStream_t stream) {
  const float* x      = (const float*)d_in[0];
  const float* w_attn = (const float*)d_in[1];
  const float* b_attn = (const float*)d_in[2];
  const float* w_proj = (const float*)d_in[3];
  const float* b_proj = (const float*)d_in[4];
  float* out = (float*)d_out;
  char* ws = (char*)d_ws;
  if (ws_size < 92274688u) return;  // need 88 MB scratch
  short* Xb  = (short*)(ws);                 // [8192][1024] bf16
  short* Wta = (short*)(ws + 16777216);      // [3072][1024] bf16 (W^T)
  short* Wtp = (short*)(ws + 23068672);      // [1024][1024] bf16 (W^T)
  short* Qb  = (short*)(ws + 25165824);      // [64 bh][2048][64]  (scaled by log2e)
  short* Kb  = (short*)(ws + 41943040);      // [64 bh][2048][64]
  short* VbT = (short*)(ws + 58720256);      // [64 bh][64 d][2048 s]
  short* A2  = (short*)(ws + 75497472);      // [8192][1024] bf16

  hipLaunchKernelGGL(k_prep, dim3(9216), dim3(256), 0, stream, x, w_attn, w_proj, Xb, Wta, Wtp);
  hipLaunchKernelGGL(k_gemm11q, dim3(768), dim3(512), 0, stream, Xb, Wta, b_attn, Qb, Kb, VbT);
  hipLaunchKernelGGL(k_attn, dim3(64, 8), dim3(256), 0, stream, Qb, Kb, VbT, A2);
  hipLaunchKernelGGL(k_gemm14p, dim3(512), dim3(256), 0, stream, A2, Wtp, b_proj, out);
}